// Round 9
// baseline (255.009 us; speedup 1.0000x reference)
//
#include <hip/hip_runtime.h>
#include <stdint.h>

// MFMA fragment types (gfx950)
typedef __attribute__((ext_vector_type(8))) short short8;  // 8 bf16 = 4 VGPRs
typedef __attribute__((ext_vector_type(4))) float f32x4;   // 4 fp32 acc / vec load

static_assert(sizeof(short8) == 16, "frag size");

__device__ __forceinline__ uint16_t f2bf(float f) {
  uint32_t u = __builtin_bit_cast(uint32_t, f);
  u += 0x7fffu + ((u >> 16) & 1u);
  return (uint16_t)(u >> 16);
}

__device__ __forceinline__ short8 pack_bf16x8(f32x4 lo, f32x4 hi) {
  union { uint32_t u[4]; short8 s; } z;
  z.u[0] = (uint32_t)f2bf(lo.x) | ((uint32_t)f2bf(lo.y) << 16);
  z.u[1] = (uint32_t)f2bf(lo.z) | ((uint32_t)f2bf(lo.w) << 16);
  z.u[2] = (uint32_t)f2bf(hi.x) | ((uint32_t)f2bf(hi.y) << 16);
  z.u[3] = (uint32_t)f2bf(hi.z) | ((uint32_t)f2bf(hi.w) << 16);
  return z.s;
}

__device__ __forceinline__ void gload_lds16(const void* g, void* lds_wave_base) {
  // async global->LDS, 16B/lane; LDS dst = wave-uniform base + lane*16
  __builtin_amdgcn_global_load_lds(
      (__attribute__((address_space(1))) void*)(void*)(g),
      (__attribute__((address_space(3))) void*)(lds_wave_base),
      16, 0, 0);
}

#define MEMFENCE() asm volatile("" ::: "memory")

// Swizzle convention (all bf16 operands): within each 64-elem K-group of a
// row, the 16B chunk at slot s holds source chunk s ^ (row & 7). Fragment
// reads at slot (h*4+q)^(r&7) recover true chunk h*4+q; any 8 consecutive
// rows spread over 8 distinct 16B columns -> conflict-free ds_read_b128
// (R0-proven: SQ_LDS_BANK_CONFLICT == 0).

// ---------------------------------------------------------------------------
// quant: dwT[o][i] = ternary(weight[i][o]) in {-1,0,+1} bf16, swizzled.
// ---------------------------------------------------------------------------
__global__ __launch_bounds__(256) void quant_kernel(const float* __restrict__ w,
                                                    uint16_t* __restrict__ dwT) {
  const int o = blockIdx.x, i = threadIdx.x;
  const float v = w[i * 256 + o];
  const float t = (v > 0.01f) ? 1.0f : ((v < -0.01f) ? -1.0f : 0.0f);
  dwT[o * 256 + (i ^ ((o & 7) << 3))] = f2bf(t);
}

// ---------------------------------------------------------------------------
// convA: adj fp32 -> adjbf bf16, SWIZZLED per convention (only launched when
// ws_size is big enough; see kernel_launch guard).
// ---------------------------------------------------------------------------
__global__ __launch_bounds__(256) void convA_kernel(const float* __restrict__ adj,
                                                    uint16_t* __restrict__ adjbf) {
#pragma unroll
  for (int it = 0; it < 8; ++it) {
    const int id = blockIdx.x * 2048 + it * 256 + threadIdx.x;
    const int row = id >> 8;                 // 0..16383 (b*2048 + n)
    const int c = id & 255;                  // dst chunk (16 B) within row
    const int srcc = (c & 248) | ((c & 7) ^ (row & 7));
    const float* p = adj + (size_t)row * 2048 + srcc * 8;
    const f32x4 v0 = *(const f32x4*)p;
    const f32x4 v1 = *(const f32x4*)(p + 4);
    uint4 u;
    u.x = (uint32_t)f2bf(v0.x) | ((uint32_t)f2bf(v0.y) << 16);
    u.y = (uint32_t)f2bf(v0.z) | ((uint32_t)f2bf(v0.w) << 16);
    u.z = (uint32_t)f2bf(v1.x) | ((uint32_t)f2bf(v1.y) << 16);
    u.w = (uint32_t)f2bf(v1.z) | ((uint32_t)f2bf(v1.w) << 16);
    *(uint4*)(adjbf + (size_t)row * 2048 + c * 8) = u;
  }
}

// ---------------------------------------------------------------------------
// support (SINGLE-PASS K=256): spt[o][g] = bf16(0.01 * sum_i x[g][i]*tern[i][o])
// R0-proven version (unchanged): tile [64 g][64 o], 64 KB LDS, spt SWIZZLED.
// ---------------------------------------------------------------------------
#define SB_A 0
#define SB_B 32768

__global__ __launch_bounds__(256) void support_kernel(const float* __restrict__ x,
                                                      const uint16_t* __restrict__ dwT,
                                                      uint16_t* __restrict__ spt) {
  __shared__ __align__(16) unsigned char smem[65536];
  const int t = threadIdx.x, lane = t & 63, w = t >> 6;
  const int r = lane & 15, q = lane >> 4;
  const int g0 = (blockIdx.x & 255) * 64;
  const int o0 = (blockIdx.x >> 8) * 64;

#pragma unroll
  for (int j = 0; j < 8; ++j) {
    const int id = j * 256 + t;              // 64 rows x 32 chunks = 2048 ids
    const int row = id >> 5, c = id & 31;
    const float* p = x + (size_t)(g0 + row) * 256 + c * 8;
    const f32x4 v0 = *(const f32x4*)p;
    const f32x4 v1 = *(const f32x4*)(p + 4);
    uint4 u;
    u.x = (uint32_t)f2bf(v0.x) | ((uint32_t)f2bf(v0.y) << 16);
    u.y = (uint32_t)f2bf(v0.z) | ((uint32_t)f2bf(v0.w) << 16);
    u.z = (uint32_t)f2bf(v1.x) | ((uint32_t)f2bf(v1.y) << 16);
    u.w = (uint32_t)f2bf(v1.z) | ((uint32_t)f2bf(v1.w) << 16);
    *(uint4*)(smem + SB_A + row * 512 + ((c ^ (row & 7)) << 4)) = u;
  }
#pragma unroll
  for (int j = 0; j < 8; ++j) {
    const int id = j * 256 + t, row = id >> 5, c = id & 31;
    gload_lds16(dwT + (size_t)(o0 + row) * 256 + c * 8,
                smem + SB_B + (size_t)(j * 256 + w * 64) * 16);
  }
  __syncthreads();

  f32x4 acc[4] = {};
#pragma unroll
  for (int h = 0; h < 8; ++h) {              // K=256 in 8 steps of 32
    short8 av, bv[4];
    const int pc = (((h * 4 + q) ^ (r & 7)) << 4);
    av = *(const short8*)(smem + SB_A + (16 * w + r) * 512 + pc);
#pragma unroll
    for (int ni = 0; ni < 4; ++ni)
      bv[ni] = *(const short8*)(smem + SB_B + (16 * ni + r) * 512 + pc);
#pragma unroll
    for (int ni = 0; ni < 4; ++ni)
      acc[ni] = __builtin_amdgcn_mfma_f32_16x16x32_bf16(av, bv[ni], acc[ni], 0, 0, 0);
  }
  __syncthreads();

  // epilogue: transpose buffer [64 o][64 g] bf16; XOR embeds the GLOBAL spt
  // swizzle (chunk c^(o&7) per 64-g group).
#pragma unroll
  for (int ni = 0; ni < 4; ++ni) {
    const int ol = 16 * ni + r;              // C col = o
#pragma unroll
    for (int reg = 0; reg < 4; ++reg) {
      const int gl = 16 * w + 4 * q + reg;   // C row = g
      const int gsw = gl ^ ((ol & 7) << 3);
      *(uint16_t*)(smem + (ol * 64 + gsw) * 2) = f2bf(acc[ni][reg] * 0.01f);
    }
  }
  __syncthreads();
#pragma unroll
  for (int it = 0; it < 2; ++it) {
    const int id = it * 256 + t, row = id >> 3, cc = id & 7;
    const uint4 u = *(const uint4*)(smem + (row * 64 + cc * 8) * 2);
    *(uint4*)(spt + (size_t)(o0 + row) * 16384 + g0 + cc * 8) = u;
  }
}

// ---------------------------------------------------------------------------
// main v9 (m97-clone economy; needs adjbf): 128x128 tile, BK=64, 4 waves,
// wave = [64 n][64 o] = 4x4 frags -> 8 DMA insts, 16 ds_read_b128, 32 MFMA
// per wave-step. Both operands VERBATIM DMA (pre-swizzled). LDS dbuf 64 KB ->
// 2 blocks/CU. 1 barrier/step. Staged bytes: A 128 + B 128 = 256 MB.
// ---------------------------------------------------------------------------
#define GA0 0u
#define GB0 16384u
#define GA1 32768u
#define GB1 49152u

__global__ __launch_bounds__(256, 2) void gcn_main_v9(const uint16_t* __restrict__ adjbf,
                                                      const uint16_t* __restrict__ spt,
                                                      const float* __restrict__ bias,
                                                      float* __restrict__ out) {
  __shared__ __align__(16) unsigned char smem[65536];
  const int t = threadIdx.x, lane = t & 63, wv = t >> 6;
  const int r = lane & 15, q = lane >> 4, rr = r & 7;
  const int wn = wv >> 1, wo = wv & 1;       // wave tile: rows wn*64, cols wo*64
  const int bb = blockIdx.x & 7;             // batch -> XCD affinity
  const int nt = (blockIdx.x >> 3) & 15;
  const int ot = blockIdx.x >> 7;
  const int n0 = nt * 128, o0 = ot * 128;
  const uint16_t* Ab = adjbf + ((size_t)bb * 2048 + n0) * 2048;
  const uint16_t* Bb = spt + (size_t)bb * 2048;   // rows stride 16384

  const int dr = lane >> 3, dc = lane & 7;
  const int rbase0 = (wv * 4) * 8 + dr;      // j adds 8

#define STAGE(K0, ABASE, BBASE)                                                \
  do {                                                                         \
    _Pragma("unroll") for (int j = 0; j < 4; ++j) {                            \
      gload_lds16(Ab + (size_t)(rbase0 + j * 8) * 2048 + (K0) + dc * 8,        \
                  smem + (ABASE) + (size_t)(wv * 4 + j) * 1024);               \
    }                                                                          \
    _Pragma("unroll") for (int j = 0; j < 4; ++j) {                            \
      gload_lds16(Bb + (size_t)(o0 + rbase0 + j * 8) * 16384 + (K0) + dc * 8,  \
                  smem + (BBASE) + (size_t)(wv * 4 + j) * 1024);               \
    }                                                                          \
    MEMFENCE();                                                                \
  } while (0)

  f32x4 acc[4][4] = {};

  STAGE(0, GA0, GB0);
  __syncthreads();

  for (int kt = 0; kt < 32; ++kt) {
    const unsigned aCur = (kt & 1) ? GA1 : GA0;
    const unsigned bCur = (kt & 1) ? GB1 : GB0;
    const unsigned aNxt = (kt & 1) ? GA0 : GA1;
    const unsigned bNxt = (kt & 1) ? GB0 : GB1;

    if (kt < 31) STAGE((kt + 1) * 64, aNxt, bNxt);   // flies under compute

#pragma unroll
    for (int h = 0; h < 2; ++h) {            // 2 k-slices of 32
      const int pc = (((h * 4 + q) ^ rr) << 4);
      short8 av[4], bv[4];
#pragma unroll
      for (int mi = 0; mi < 4; ++mi)
        av[mi] = *(const short8*)(smem + aCur + (wn * 64 + 16 * mi + r) * 128 + pc);
#pragma unroll
      for (int ni = 0; ni < 4; ++ni)
        bv[ni] = *(const short8*)(smem + bCur + (wo * 64 + 16 * ni + r) * 128 + pc);
#pragma unroll
      for (int mi = 0; mi < 4; ++mi)
#pragma unroll
        for (int ni = 0; ni < 4; ++ni)
          acc[mi][ni] = __builtin_amdgcn_mfma_f32_16x16x32_bf16(av[mi], bv[ni],
                                                                acc[mi][ni], 0, 0, 0);
    }
    __syncthreads();                         // drains DMA(t+1) + all ds_reads
  }

#pragma unroll
  for (int ni = 0; ni < 4; ++ni) {
    const int o = o0 + wo * 64 + 16 * ni + r;
    const float bs = bias[o];
#pragma unroll
    for (int mi = 0; mi < 4; ++mi)
#pragma unroll
      for (int reg = 0; reg < 4; ++reg) {
        const int n = n0 + wn * 64 + 16 * mi + 4 * q + reg;
        out[((size_t)bb * 2048 + n) * 256 + o] = fmaxf(acc[mi][ni][reg] + bs, 0.0f);
      }
  }
#undef STAGE
}

// ---------------------------------------------------------------------------
// main v8 (R7-proven fallback, passed at 228.8us total): BM=64, depth-2
// counted-vmcnt pure-DMA pipeline, A staged raw fp32. Used when ws_size is
// too small for adjbf.
// ---------------------------------------------------------------------------
#define MBUF0 0u
#define MBUF1 49152u
#define MBUF2 98304u
#define MB_BOFF 16384u

__global__ __launch_bounds__(512, 2) void gcn_main_v8(const float* __restrict__ adj,
                                                      const uint16_t* __restrict__ spt,
                                                      const float* __restrict__ bias,
                                                      float* __restrict__ out) {
  __shared__ __align__(16) unsigned char smem[147456];   // 3 x 48 KB
  const int t = threadIdx.x, lane = t & 63, wv = t >> 6;
  const int r = lane & 15, q = lane >> 4;
  const int wn = wv >> 2;
  const int oq = wv & 3;
  const int bb = blockIdx.x & 7;
  const int n0 = (blockIdx.x >> 3) * 64;
  const float* adjb = adj + ((size_t)bb * 2048 + n0) * 2048;
  const uint16_t* sptb = spt + (size_t)bb * 2048;

  const int aRow0 = wv * 8 + (lane >> 4);
  const int aCl = lane & 15;
  const int aCs0 = (aCl & 8) | ((aCl & 7) ^ (aRow0 & 7));
  const int aCs1 = (aCl & 8) | ((aCl & 7) ^ ((aRow0 + 4) & 7));
  const float* aSrc0 = adjb + (size_t)aRow0 * 2048 + aCs0 * 4;
  const float* aSrc1 = adjb + (size_t)(aRow0 + 4) * 2048 + aCs1 * 4;
  const unsigned aDst0 = (unsigned)(wv * 2) * 1024u;
  const unsigned aDst1 = aDst0 + 1024u;

  const int bRowIn = lane >> 3, bCl = lane & 7;

#define STAGE(K0, BASE)                                                        \
  do {                                                                         \
    gload_lds16(aSrc0 + (K0), smem + (BASE) + aDst0);                          \
    gload_lds16(aSrc1 + (K0), smem + (BASE) + aDst1);                          \
    _Pragma("unroll") for (int j = 0; j < 4; ++j) {                            \
      const int row_ = (4 * wv + j) * 8 + bRowIn;                              \
      gload_lds16(sptb + (size_t)row_ * 16384 + (K0) + bCl * 8,                \
                  smem + (BASE) + MB_BOFF + (size_t)(4 * wv + j) * 1024);      \
    }                                                                          \
    MEMFENCE();                                                                \
  } while (0)

  f32x4 acc[2][4] = {};
  const int rr = r & 7;

  STAGE(0, MBUF0);
  STAGE(64, MBUF1);
  asm volatile("s_waitcnt vmcnt(6)" ::: "memory");
  __builtin_amdgcn_s_barrier();

  unsigned bufCur = MBUF0, bufNxt = MBUF1, bufNxt2 = MBUF2;

  for (int kt = 0; kt < 32; ++kt) {
    if (kt < 30) STAGE((kt + 2) * 64, bufNxt2);

#pragma unroll
    for (int h = 0; h < 2; ++h) {
      short8 av[2], bv[4];
#pragma unroll
      for (int mi = 0; mi < 2; ++mi) {
        const int row = wn * 32 + mi * 16 + r;
        const int g0 = h * 8 + 2 * q;
        const int c0 = (g0 & 8) | ((g0 & 7) ^ (row & 7));
        const int c1 = (g0 & 8) | (((g0 + 1) & 7) ^ (row & 7));
        const f32x4 a0 = *(const f32x4*)(smem + bufCur + row * 256 + c0 * 16);
        const f32x4 a1 = *(const f32x4*)(smem + bufCur + row * 256 + c1 * 16);
        av[mi] = pack_bf16x8(a0, a1);
      }
      const int pc = (((h * 4 + q) ^ rr) << 4);
#pragma unroll
      for (int ni = 0; ni < 4; ++ni)
        bv[ni] = *(const short8*)(smem + bufCur + MB_BOFF +
                                  (oq * 64 + 16 * ni + r) * 128 + pc);
#pragma unroll
      for (int mi = 0; mi < 2; ++mi)
#pragma unroll
        for (int ni = 0; ni < 4; ++ni)
          acc[mi][ni] = __builtin_amdgcn_mfma_f32_16x16x32_bf16(av[mi], bv[ni],
                                                                acc[mi][ni], 0, 0, 0);
    }

    if (kt < 31) {
      if (kt < 30) {
        asm volatile("s_waitcnt vmcnt(6)" ::: "memory");
      } else {
        asm volatile("s_waitcnt vmcnt(0)" ::: "memory");
      }
      __builtin_amdgcn_s_barrier();
      const unsigned tmp = bufCur; bufCur = bufNxt; bufNxt = bufNxt2; bufNxt2 = tmp;
    }
  }

#pragma unroll
  for (int ni = 0; ni < 4; ++ni) {
    const int o = oq * 64 + 16 * ni + r;
    const float bs = bias[o];
#pragma unroll
    for (int mi = 0; mi < 2; ++mi)
#pragma unroll
      for (int reg = 0; reg < 4; ++reg) {
        const int n = n0 + wn * 32 + mi * 16 + 4 * q + reg;
        out[((size_t)bb * 2048 + n) * 256 + o] = fmaxf(acc[mi][ni][reg] + bs, 0.0f);
      }
  }
#undef STAGE
}

// ---------------------------------------------------------------------------
extern "C" void kernel_launch(void* const* d_in, const int* in_sizes, int n_in,
                              void* d_out, int out_size, void* d_ws, size_t ws_size,
                              hipStream_t stream) {
  const float* x      = (const float*)d_in[0];  // [8,2048,256]
  const float* adj    = (const float*)d_in[1];  // [8,2048,2048]
  const float* weight = (const float*)d_in[2];  // [256,256]
  const float* bias   = (const float*)d_in[3];  // [256]
  float* out = (float*)d_out;                   // [8,2048,256]

  uint16_t* dwT = (uint16_t*)d_ws;                          // 128 KB
  uint16_t* spt = (uint16_t*)((char*)d_ws + 131072);        // 8 MB

  hipLaunchKernelGGL(quant_kernel,   dim3(256),  dim3(256), 0, stream, weight, dwT);
  hipLaunchKernelGGL(support_kernel, dim3(1024), dim3(256), 0, stream, x, dwT, spt);

  // adjbf needs 64 MB at offset 8.1875 MB -> total 75,628,544 B. R8 launched
  // it unconditionally and (most likely) overflowed the workspace -> container
  // crash. Guard on ws_size; otherwise use the R7-proven fallback main.
  const size_t NEED = 131072u + 8388608u + 67108864u;
  if (ws_size >= NEED) {
    uint16_t* adjbf = (uint16_t*)((char*)d_ws + 131072 + 8388608);
    hipLaunchKernelGGL(convA_kernel, dim3(2048), dim3(256), 0, stream, adj, adjbf);
    hipLaunchKernelGGL(gcn_main_v9,  dim3(256),  dim3(256), 0, stream, adjbf, spt, bias, out);
  } else {
    hipLaunchKernelGGL(gcn_main_v8,  dim3(256),  dim3(512), 0, stream, adj, spt, bias, out);
  }
}

// Round 10
// 229.682 us; speedup vs baseline: 1.1103x; 1.1103x over previous
//
#include <hip/hip_runtime.h>
#include <stdint.h>

// MFMA fragment types (gfx950)
typedef __attribute__((ext_vector_type(8))) short short8;  // 8 bf16 = 4 VGPRs
typedef __attribute__((ext_vector_type(4))) float f32x4;   // 4 fp32 acc / vec load

static_assert(sizeof(short8) == 16, "frag size");

__device__ __forceinline__ uint16_t f2bf(float f) {
  uint32_t u = __builtin_bit_cast(uint32_t, f);
  u += 0x7fffu + ((u >> 16) & 1u);
  return (uint16_t)(u >> 16);
}

__device__ __forceinline__ short8 pack_bf16x8(f32x4 lo, f32x4 hi) {
  union { uint32_t u[4]; short8 s; } z;
  z.u[0] = (uint32_t)f2bf(lo.x) | ((uint32_t)f2bf(lo.y) << 16);
  z.u[1] = (uint32_t)f2bf(lo.z) | ((uint32_t)f2bf(lo.w) << 16);
  z.u[2] = (uint32_t)f2bf(hi.x) | ((uint32_t)f2bf(hi.y) << 16);
  z.u[3] = (uint32_t)f2bf(hi.z) | ((uint32_t)f2bf(hi.w) << 16);
  return z.s;
}

__device__ __forceinline__ void gload_lds16(const void* g, void* lds_wave_base) {
  // async global->LDS, 16B/lane; LDS dst = wave-uniform base + lane*16
  __builtin_amdgcn_global_load_lds(
      (__attribute__((address_space(1))) void*)(void*)(g),
      (__attribute__((address_space(3))) void*)(lds_wave_base),
      16, 0, 0);
}

#define MEMFENCE() asm volatile("" ::: "memory")

// Swizzle convention (bf16 operands): within each 64-elem K-group of a row,
// 16B chunk slot s holds source chunk s ^ (row & 7). Fragment reads at slot
// (h*4+q)^(r&7) recover chunk h*4+q, conflict-free (R0: 0 conflicts).
// fp32 A staging uses the same XOR on the low 3 bits of the 16B-chunk index
// ((c&8)|((c&7)^(row&7))): reads are ~8-way conflicted (structural: 256B
// bank-aligned rows, 8 bank-groups) — accepted, it replaces a 33us convA pass.

// ---------------------------------------------------------------------------
// quant: dwT[o][i] = ternary(weight[i][o]) in {-1,0,+1} bf16, swizzled.
// ---------------------------------------------------------------------------
__global__ __launch_bounds__(256) void quant_kernel(const float* __restrict__ w,
                                                    uint16_t* __restrict__ dwT) {
  const int o = blockIdx.x, i = threadIdx.x;
  const float v = w[i * 256 + o];
  const float t = (v > 0.01f) ? 1.0f : ((v < -0.01f) ? -1.0f : 0.0f);
  dwT[o * 256 + (i ^ ((o & 7) << 3))] = f2bf(t);
}

// ---------------------------------------------------------------------------
// support (SINGLE-PASS K=256): spt[o][g] = bf16(0.01 * sum_i x[g][i]*tern[i][o])
// R0-proven version (unchanged): tile [64 g][64 o], 64 KB LDS, spt SWIZZLED
// (chunk c^(o&7) within each 64-g group; main's B-DMA stages it verbatim).
// ---------------------------------------------------------------------------
#define SB_A 0
#define SB_B 32768

__global__ __launch_bounds__(256) void support_kernel(const float* __restrict__ x,
                                                      const uint16_t* __restrict__ dwT,
                                                      uint16_t* __restrict__ spt) {
  __shared__ __align__(16) unsigned char smem[65536];
  const int t = threadIdx.x, lane = t & 63, w = t >> 6;
  const int r = lane & 15, q = lane >> 4;
  const int g0 = (blockIdx.x & 255) * 64;
  const int o0 = (blockIdx.x >> 8) * 64;

#pragma unroll
  for (int j = 0; j < 8; ++j) {
    const int id = j * 256 + t;              // 64 rows x 32 chunks = 2048 ids
    const int row = id >> 5, c = id & 31;
    const float* p = x + (size_t)(g0 + row) * 256 + c * 8;
    const f32x4 v0 = *(const f32x4*)p;
    const f32x4 v1 = *(const f32x4*)(p + 4);
    uint4 u;
    u.x = (uint32_t)f2bf(v0.x) | ((uint32_t)f2bf(v0.y) << 16);
    u.y = (uint32_t)f2bf(v0.z) | ((uint32_t)f2bf(v0.w) << 16);
    u.z = (uint32_t)f2bf(v1.x) | ((uint32_t)f2bf(v1.y) << 16);
    u.w = (uint32_t)f2bf(v1.z) | ((uint32_t)f2bf(v1.w) << 16);
    *(uint4*)(smem + SB_A + row * 512 + ((c ^ (row & 7)) << 4)) = u;
  }
#pragma unroll
  for (int j = 0; j < 8; ++j) {
    const int id = j * 256 + t, row = id >> 5, c = id & 31;
    gload_lds16(dwT + (size_t)(o0 + row) * 256 + c * 8,
                smem + SB_B + (size_t)(j * 256 + w * 64) * 16);
  }
  __syncthreads();

  f32x4 acc[4] = {};
#pragma unroll
  for (int h = 0; h < 8; ++h) {              // K=256 in 8 steps of 32
    short8 av, bv[4];
    const int pc = (((h * 4 + q) ^ (r & 7)) << 4);
    av = *(const short8*)(smem + SB_A + (16 * w + r) * 512 + pc);
#pragma unroll
    for (int ni = 0; ni < 4; ++ni)
      bv[ni] = *(const short8*)(smem + SB_B + (16 * ni + r) * 512 + pc);
#pragma unroll
    for (int ni = 0; ni < 4; ++ni)
      acc[ni] = __builtin_amdgcn_mfma_f32_16x16x32_bf16(av, bv[ni], acc[ni], 0, 0, 0);
  }
  __syncthreads();

  // epilogue: transpose buffer [64 o][64 g] bf16; copy-out leaves the GLOBAL
  // spt swizzled (chunk c^(o&7) per 64-g group).
#pragma unroll
  for (int ni = 0; ni < 4; ++ni) {
    const int ol = 16 * ni + r;              // C col = o
#pragma unroll
    for (int reg = 0; reg < 4; ++reg) {
      const int gl = 16 * w + 4 * q + reg;   // C row = g
      const int gsw = gl ^ ((ol & 7) << 3);
      *(uint16_t*)(smem + (ol * 64 + gsw) * 2) = f2bf(acc[ni][reg] * 0.01f);
    }
  }
  __syncthreads();
#pragma unroll
  for (int it = 0; it < 2; ++it) {
    const int id = it * 256 + t, row = id >> 3, cc = id & 7;
    const uint4 u = *(const uint4*)(smem + (row * 64 + cc * 8) * 2);
    *(uint4*)(spt + (size_t)(o0 + row) * 16384 + g0 + cc * 8) = u;
  }
}

// ---------------------------------------------------------------------------
// main v10 (4x4 economy + depth-2 counted vmcnt + fp32-A direct, no convA):
//   out = relu(adj @ spt + bias)
// R9 accounting: v9 ~55us (1 block/CU, vmcnt(0) drain exposed every step);
// convA +33us ate the economy gain. v10 = v9's 128x128/BK=64/4-wave shape
// + R7's triple-buffer depth-2 pipeline (stage t+2 issued at step t,
// pre-barrier vmcnt(12) keeps it in flight -> 2 full steps of slack) + A
// staged as RAW FP32 straight from adj (no conversion pass; packed at
// fragment read). Per block-step: A 32 KB (8 insts/wave) + B 16 KB (4) =
// 12 DMA insts/wave. LDS 3 x 48 KB = 144 KB. 1 barrier/step.
// Staged totals: A 134 MB fp32 (once) + B 128 MB (16 re-reads) = 262 MB.
// ---------------------------------------------------------------------------
#define VBUFSZ 49152u   // per-buffer: A fp32 32 KB @0, B bf16 16 KB @32768
#define VB_B 32768u

__global__ __launch_bounds__(256) void gcn_main_kernel(const float* __restrict__ adj,
                                                       const uint16_t* __restrict__ spt,
                                                       const float* __restrict__ bias,
                                                       float* __restrict__ out) {
  __shared__ __align__(16) unsigned char smem[147456];   // 3 x 48 KB
  const int t = threadIdx.x, lane = t & 63, wv = t >> 6;
  const int r = lane & 15, q = lane >> 4, rr = r & 7;
  const int wn = wv >> 1, wo = wv & 1;       // wave tile: rows wn*64, cols wo*64
  const int bb = blockIdx.x & 7;             // batch -> XCD affinity
  const int nt = (blockIdx.x >> 3) & 15;
  const int ot = blockIdx.x >> 7;
  const int n0 = nt * 128, o0 = ot * 128;
  const float* Ab = adj + ((size_t)bb * 2048 + n0) * 2048;
  const uint16_t* Bb = spt + (size_t)bb * 2048;   // rows stride 16384

  // A-DMA (8 insts/wave/stage): inst j covers rows wv*32+j*4 .. +4
  // (4 rows x 256 B fp32). lane -> row +(lane>>4), slot lane&15; source
  // chunk inverse-swizzled: cs = (cl&8)|((cl&7)^(row&7)).
  const int aRowL = lane >> 4, aCl = lane & 15;
  // B-DMA (4 insts/wave/stage): inst j covers rows (wv*4+j)*8 .. +8
  // (8 rows x 128 B bf16), verbatim (spt pre-swizzled).
  const int bRowL = lane >> 3, bCl = lane & 7;

#define STAGE(K0, BASE)                                                        \
  do {                                                                         \
    _Pragma("unroll") for (int j = 0; j < 8; ++j) {                            \
      const int row_ = wv * 32 + j * 4 + aRowL;                                \
      const int cs_ = (aCl & 8) | ((aCl & 7) ^ (row_ & 7));                    \
      gload_lds16(Ab + (size_t)row_ * 2048 + (K0) + cs_ * 4,                   \
                  smem + (BASE) + (size_t)(wv * 8 + j) * 1024);                \
    }                                                                          \
    _Pragma("unroll") for (int j = 0; j < 4; ++j) {                            \
      const int row_ = (wv * 4 + j) * 8 + bRowL;                               \
      gload_lds16(Bb + (size_t)(o0 + row_) * 16384 + (K0) + bCl * 8,           \
                  smem + (BASE) + VB_B + (size_t)(wv * 4 + j) * 1024);         \
    }                                                                          \
    MEMFENCE();                                                                \
  } while (0)

  f32x4 acc[4][4] = {};

  // prologue: stage steps 0,1; publish buf0 (drain its 12, keep stage1's 12)
  STAGE(0, 0u);
  STAGE(64, VBUFSZ);
  asm volatile("s_waitcnt vmcnt(12)" ::: "memory");
  __builtin_amdgcn_s_barrier();

  unsigned bufCur = 0u, bufNxt = VBUFSZ, bufNxt2 = 2u * VBUFSZ;

  for (int kt = 0; kt < 32; ++kt) {
    if (kt < 30) STAGE((kt + 2) * 64, bufNxt2);      // 2 steps of slack

#pragma unroll
    for (int h = 0; h < 2; ++h) {            // 2 k-slices of 32
      short8 av[4], bv[4];
#pragma unroll
      for (int mi = 0; mi < 4; ++mi) {       // A: fp32 -> bf16 at read
        const int row = wn * 64 + 16 * mi + r;
        const int g = h * 8 + 2 * q;
        const int c0 = (g & 8) | ((g & 7) ^ rr);
        const int c1 = (g & 8) | (((g + 1) & 7) ^ rr);
        const f32x4 a0 = *(const f32x4*)(smem + bufCur + row * 256 + c0 * 16);
        const f32x4 a1 = *(const f32x4*)(smem + bufCur + row * 256 + c1 * 16);
        av[mi] = pack_bf16x8(a0, a1);
      }
      const int pc = (((h * 4 + q) ^ rr) << 4);
#pragma unroll
      for (int ni = 0; ni < 4; ++ni)
        bv[ni] = *(const short8*)(smem + bufCur + VB_B +
                                  (wo * 64 + 16 * ni + r) * 128 + pc);
#pragma unroll
      for (int mi = 0; mi < 4; ++mi)
#pragma unroll
        for (int ni = 0; ni < 4; ++ni)
          acc[mi][ni] = __builtin_amdgcn_mfma_f32_16x16x32_bf16(av[mi], bv[ni],
                                                                acc[mi][ni], 0, 0, 0);
    }

    if (kt < 31) {
      if (kt < 30) {
        // drain stage(t+1) (publishing bufNxt), keep stage(t+2)'s 12 in flight
        asm volatile("s_waitcnt vmcnt(12)" ::: "memory");
      } else {
        asm volatile("s_waitcnt vmcnt(0)" ::: "memory");  // tail: drain stage 31
      }
      __builtin_amdgcn_s_barrier();
      const unsigned tmp = bufCur; bufCur = bufNxt; bufNxt = bufNxt2; bufNxt2 = tmp;
    }
  }

  // epilogue: +bias, relu, fp32 store
#pragma unroll
  for (int ni = 0; ni < 4; ++ni) {
    const int o = o0 + wo * 64 + 16 * ni + r;      // C col = N = o
    const float bs = bias[o];
#pragma unroll
    for (int mi = 0; mi < 4; ++mi)
#pragma unroll
      for (int reg = 0; reg < 4; ++reg) {
        const int n = n0 + wn * 64 + 16 * mi + 4 * q + reg;  // C row = M = n
        out[((size_t)bb * 2048 + n) * 256 + o] = fmaxf(acc[mi][ni][reg] + bs, 0.0f);
      }
  }
#undef STAGE
}

// ---------------------------------------------------------------------------
extern "C" void kernel_launch(void* const* d_in, const int* in_sizes, int n_in,
                              void* d_out, int out_size, void* d_ws, size_t ws_size,
                              hipStream_t stream) {
  const float* x      = (const float*)d_in[0];  // [8,2048,256]
  const float* adj    = (const float*)d_in[1];  // [8,2048,2048]
  const float* weight = (const float*)d_in[2];  // [256,256]
  const float* bias   = (const float*)d_in[3];  // [256]
  float* out = (float*)d_out;                   // [8,2048,256]

  uint16_t* dwT = (uint16_t*)d_ws;                          // 128 KB
  uint16_t* spt = (uint16_t*)((char*)d_ws + 131072);        // 8 MB

  hipLaunchKernelGGL(quant_kernel,    dim3(256),  dim3(256), 0, stream, weight, dwT);
  hipLaunchKernelGGL(support_kernel,  dim3(1024), dim3(256), 0, stream, x, dwT, spt);
  hipLaunchKernelGGL(gcn_main_kernel, dim3(256),  dim3(256), 0, stream, adj, spt, bias, out);
}